// Round 10
// baseline (101585.266 us; speedup 1.0000x reference)
//
#include <hip/hip_runtime.h>
#include <math.h>

#define HID 2048
#define SEQ 2048
#define N3  6144   // 3*HID
#define NBLK 256
#define NREG 8     // replicated exchange regions (contention spread)

// ---------------------------------------------------------------------------
// GEMM: GI = X @ W_ih^T + b_ih   (fp32, classic 128x128x16 LDS tile, 8x8/thread)
// ---------------------------------------------------------------------------
#define BM 128
#define BN 128
#define BK 16

__global__ __launch_bounds__(256)
void gi_gemm_kernel(const float* __restrict__ X, const float* __restrict__ W,
                    const float* __restrict__ bias, float* __restrict__ GI) {
  __shared__ float As[BK][BM + 4];
  __shared__ float Bs[BK][BN + 4];
  const int tid = threadIdx.x;
  const int bm = blockIdx.y * BM;
  const int bn = blockIdx.x * BN;
  const int tx = tid & 15;
  const int ty = tid >> 4;
  const int lr = tid >> 1;
  const int lk = (tid & 1) * 8;

  float acc[8][8];
#pragma unroll
  for (int i = 0; i < 8; ++i)
#pragma unroll
    for (int j = 0; j < 8; ++j) acc[i][j] = 0.f;

  const float* Arow = X + (size_t)(bm + lr) * HID + lk;
  const float* Brow = W + (size_t)(bn + lr) * HID + lk;

  for (int kc = 0; kc < HID; kc += BK) {
    float4 a0 = *(const float4*)(Arow + kc);
    float4 a1 = *(const float4*)(Arow + kc + 4);
    float4 b0 = *(const float4*)(Brow + kc);
    float4 b1 = *(const float4*)(Brow + kc + 4);
    __syncthreads();
    As[lk + 0][lr] = a0.x; As[lk + 1][lr] = a0.y; As[lk + 2][lr] = a0.z; As[lk + 3][lr] = a0.w;
    As[lk + 4][lr] = a1.x; As[lk + 5][lr] = a1.y; As[lk + 6][lr] = a1.z; As[lk + 7][lr] = a1.w;
    Bs[lk + 0][lr] = b0.x; Bs[lk + 1][lr] = b0.y; Bs[lk + 2][lr] = b0.z; Bs[lk + 3][lr] = b0.w;
    Bs[lk + 4][lr] = b1.x; Bs[lk + 5][lr] = b1.y; Bs[lk + 6][lr] = b1.z; Bs[lk + 7][lr] = b1.w;
    __syncthreads();
#pragma unroll
    for (int kk = 0; kk < BK; ++kk) {
      float4 av0 = *(const float4*)&As[kk][ty * 8];
      float4 av1 = *(const float4*)&As[kk][ty * 8 + 4];
      float4 bv0 = *(const float4*)&Bs[kk][tx * 8];
      float4 bv1 = *(const float4*)&Bs[kk][tx * 8 + 4];
      float a[8] = {av0.x, av0.y, av0.z, av0.w, av1.x, av1.y, av1.z, av1.w};
      float b[8] = {bv0.x, bv0.y, bv0.z, bv0.w, bv1.x, bv1.y, bv1.z, bv1.w};
#pragma unroll
      for (int i = 0; i < 8; ++i)
#pragma unroll
        for (int j = 0; j < 8; ++j)
          acc[i][j] = fmaf(a[i], b[j], acc[i][j]);
    }
  }

  const int n0 = bn + tx * 8;
  float bv[8];
#pragma unroll
  for (int j = 0; j < 8; ++j) bv[j] = bias[n0 + j];
#pragma unroll
  for (int i = 0; i < 8; ++i) {
    float4 o0, o1;
    o0.x = acc[i][0] + bv[0]; o0.y = acc[i][1] + bv[1];
    o0.z = acc[i][2] + bv[2]; o0.w = acc[i][3] + bv[3];
    o1.x = acc[i][4] + bv[4]; o1.y = acc[i][5] + bv[5];
    o1.z = acc[i][6] + bv[6]; o1.w = acc[i][7] + bv[7];
    float* Crow = GI + (size_t)(bm + ty * 8 + i) * N3 + n0;
    *(float4*)Crow = o0;
    *(float4*)(Crow + 4) = o1;
  }
}

// ---------------------------------------------------------------------------
// Persistent recurrent kernel == R9 structure, but with ACQUIRE poll loads and
// RELEASE producer stores: per the R9 counters (VALUBusy 21% => ~25 poll
// rounds/step => ~6000-cyc store->load visibility), relaxed agent atomics
// appear to be served from the consumer's stale XCD-L2; acquire forces the
// canonical load+buffer_inv sequence (fresh L3 data every retry round) and
// release guarantees prompt write-through of the producer store.
// ---------------------------------------------------------------------------
__device__ __forceinline__ unsigned long long ld_pair(const unsigned long long* p) {
  return __hip_atomic_load(p, __ATOMIC_ACQUIRE, __HIP_MEMORY_SCOPE_AGENT);
}

template <int CTRL, int ROW_MASK>
__device__ __forceinline__ float dpp_add(float x) {
  int y = __builtin_amdgcn_update_dpp(0, __float_as_uint(x), CTRL, ROW_MASK, 0xf, true);
  return x + __uint_as_float(y);
}

__device__ __forceinline__ float wave_sum(float x) {
  x = dpp_add<0x111, 0xf>(x);  // row_shr:1
  x = dpp_add<0x112, 0xf>(x);  // row_shr:2
  x = dpp_add<0x114, 0xf>(x);  // row_shr:4
  x = dpp_add<0x118, 0xf>(x);  // row_shr:8
  x = dpp_add<0x142, 0xa>(x);  // row_bcast:15, rows 1,3
  x = dpp_add<0x143, 0xc>(x);  // row_bcast:31, rows 2,3
  return __uint_as_float(__builtin_amdgcn_readlane(__float_as_uint(x), 63));
}

__device__ __forceinline__ float rlane(float x, int l) {
  return __uint_as_float(__builtin_amdgcn_readlane(__float_as_uint(x), l));
}

__device__ __forceinline__ float sigf(float x) {
  return __builtin_amdgcn_rcpf(1.f + __expf(-x));
}
__device__ __forceinline__ float tanhfast(float x) {
  return 1.f - 2.f * __builtin_amdgcn_rcpf(1.f + __expf(2.f * x));
}

__device__ __forceinline__ float unpk24(unsigned u) {           // low 24 bits -> fp32
  return __uint_as_float((u & 0x00FFFFFFu) << 8);
}

__global__ __launch_bounds__(256, 1)
void gru_recurrent_kernel(const float* __restrict__ Whh,
                          const float* __restrict__ bhh,
                          const float* __restrict__ GI,      // [t1-t0][N3]
                          float* __restrict__ out,
                          unsigned long long* hpk,           // [NREG][2][HID/2]
                          int t0, int t1) {
  __shared__ float lds_h[2][HID];
  const int tid  = threadIdx.x;
  const int lane = tid & 63;
  const int wv   = tid >> 6;
  const int gw   = blockIdx.x * 4 + wv;   // 0..1023 == this wave's pair-slot
  const int i0   = 2 * gw;
  const int reg  = blockIdx.x & (NREG - 1);

  const int rows[6] = {i0, i0 + 1, HID + i0, HID + i0 + 1, 2 * HID + i0, 2 * HID + i0 + 1};

  // Weights pinned in AGPRs: w[r][jb] covers k = jb*256 + lane*4 + {0..3}
  float4 w[6][8];
#pragma unroll
  for (int r = 0; r < 6; ++r) {
    const float* wr = Whh + (size_t)rows[r] * HID + lane * 4;
#pragma unroll
    for (int jb = 0; jb < 8; ++jb) {
      w[r][jb] = *(const float4*)(wr + jb * 256);
      asm volatile("" : "+a"(w[r][jb].x), "+a"(w[r][jb].y),
                        "+a"(w[r][jb].z), "+a"(w[r][jb].w));
    }
  }

  // wave-uniform biases for the wave's two units
  float br0, br1, bz0, bz1, bn0, bn1;
  {
    float a = 0.f, b = 0.f, c = 0.f;
    if (lane < 2) {
      a = bhh[i0 + lane];
      b = bhh[HID + i0 + lane];
      c = bhh[2 * HID + i0 + lane];
    }
    br0 = rlane(a, 0); br1 = rlane(a, 1);
    bz0 = rlane(b, 0); bz1 = rlane(b, 1);
    bn0 = rlane(c, 0); bn1 = rlane(c, 1);
  }

  // GI prefetch for first step
  float gr = 0.f, gz = 0.f, gn = 0.f;
  if (lane < 2) {
    gr = GI[i0 + lane];
    gz = GI[HID + i0 + lane];
    gn = GI[2 * HID + i0 + lane];
  }

  const int s0 = tid * 2;   // this thread's first pair-slot in each half

  for (int t = t0; t < t1; ++t) {
    // ---- batched-retry poll: 4 packed pair-slots (8 units) per thread ----
    const unsigned long long* hb = hpk + ((size_t)reg * 2 + (t & 1)) * (HID / 2);
    const unsigned tb = (unsigned)t & 0xFFu;
    const unsigned long long pat =
        ((unsigned long long)tb << 24) | ((unsigned long long)tb << 56);
    const unsigned long long msk = 0xFF000000FF000000ULL;
    unsigned long long q0 = ld_pair(hb + s0);
    unsigned long long q1 = ld_pair(hb + s0 + 1);
    unsigned long long q2 = ld_pair(hb + 512 + s0);
    unsigned long long q3 = ld_pair(hb + 512 + s0 + 1);
    for (;;) {
      int stale = 0;
      stale |= ((q0 & msk) != pat) ? 1 : 0;
      stale |= ((q1 & msk) != pat) ? 2 : 0;
      stale |= ((q2 & msk) != pat) ? 4 : 0;
      stale |= ((q3 & msk) != pat) ? 8 : 0;
      if (!stale) break;
      if (stale & 1) q0 = ld_pair(hb + s0);
      if (stale & 2) q1 = ld_pair(hb + s0 + 1);
      if (stale & 4) q2 = ld_pair(hb + 512 + s0);
      if (stale & 8) q3 = ld_pair(hb + 512 + s0 + 1);
    }

    float* lc = lds_h[t & 1];
    float4 v0, v1;
    v0.x = unpk24((unsigned)q0); v0.y = unpk24((unsigned)(q0 >> 32));
    v0.z = unpk24((unsigned)q1); v0.w = unpk24((unsigned)(q1 >> 32));
    v1.x = unpk24((unsigned)q2); v1.y = unpk24((unsigned)(q2 >> 32));
    v1.z = unpk24((unsigned)q3); v1.w = unpk24((unsigned)(q3 >> 32));
    *(float4*)&lc[tid * 4] = v0;
    *(float4*)&lc[1024 + tid * 4] = v1;

    // GI prefetch (pre-barrier, independent of h)
    float pr = 0.f, pz = 0.f, pn = 0.f;
    if (t + 1 < t1 && lane < 2) {
      const float* g = GI + (size_t)(t + 1 - t0) * N3;
      pr = g[i0 + lane];
      pz = g[HID + i0 + lane];
      pn = g[2 * HID + i0 + lane];
    }
    __syncthreads();

    // ---- matvec: 6 rows x 2048 (weights in AGPRs) ----
    float acc0 = 0.f, acc1 = 0.f, acc2 = 0.f, acc3 = 0.f, acc4 = 0.f, acc5 = 0.f;
#pragma unroll
    for (int jb = 0; jb < 8; ++jb) {
      float4 hv = *(const float4*)&lc[jb * 256 + lane * 4];
      acc0 = fmaf(w[0][jb].x, hv.x, acc0); acc0 = fmaf(w[0][jb].y, hv.y, acc0);
      acc0 = fmaf(w[0][jb].z, hv.z, acc0); acc0 = fmaf(w[0][jb].w, hv.w, acc0);
      acc1 = fmaf(w[1][jb].x, hv.x, acc1); acc1 = fmaf(w[1][jb].y, hv.y, acc1);
      acc1 = fmaf(w[1][jb].z, hv.z, acc1); acc1 = fmaf(w[1][jb].w, hv.w, acc1);
      acc2 = fmaf(w[2][jb].x, hv.x, acc2); acc2 = fmaf(w[2][jb].y, hv.y, acc2);
      acc2 = fmaf(w[2][jb].z, hv.z, acc2); acc2 = fmaf(w[2][jb].w, hv.w, acc2);
      acc3 = fmaf(w[3][jb].x, hv.x, acc3); acc3 = fmaf(w[3][jb].y, hv.y, acc3);
      acc3 = fmaf(w[3][jb].z, hv.z, acc3); acc3 = fmaf(w[3][jb].w, hv.w, acc3);
      acc4 = fmaf(w[4][jb].x, hv.x, acc4); acc4 = fmaf(w[4][jb].y, hv.y, acc4);
      acc4 = fmaf(w[4][jb].z, hv.z, acc4); acc4 = fmaf(w[4][jb].w, hv.w, acc4);
      acc5 = fmaf(w[5][jb].x, hv.x, acc5); acc5 = fmaf(w[5][jb].y, hv.y, acc5);
      acc5 = fmaf(w[5][jb].z, hv.z, acc5); acc5 = fmaf(w[5][jb].w, hv.w, acc5);
    }

    // ---- DPP reduce -> wave-uniform sums ----
    const float sr0 = wave_sum(acc0), sr1 = wave_sum(acc1);
    const float sz0 = wave_sum(acc2), sz1 = wave_sum(acc3);
    const float sn0 = wave_sum(acc4), sn1 = wave_sum(acc5);

    const float gr0 = rlane(gr, 0), gr1 = rlane(gr, 1);
    const float gz0 = rlane(gz, 0), gz1 = rlane(gz, 1);
    const float gn0 = rlane(gn, 0), gn1 = rlane(gn, 1);

    const float r0 = sigf(gr0 + sr0 + br0);
    const float r1 = sigf(gr1 + sr1 + br1);
    const float z0 = sigf(gz0 + sz0 + bz0);
    const float z1 = sigf(gz1 + sz1 + bz1);
    const float n0 = tanhfast(gn0 + r0 * (sn0 + bn0));
    const float n1 = tanhfast(gn1 + r1 * (sn1 + bn1));
    const float hp0 = lc[i0], hp1 = lc[i0 + 1];
    const float hn0 = (1.f - z0) * n0 + z0 * hp0;   // wave-uniform
    const float hn1 = (1.f - z1) * n1 + z1 * hp1;   // wave-uniform

    // ---- pack (tag8|fp24)x2, RELEASE-store to 8 regions, one instruction ----
    {
      const unsigned nt = ((unsigned)(t + 1) & 0xFFu) << 24;
      const unsigned u0 = (__float_as_uint(hn0) + 0x80u) >> 8;   // round-half-up
      const unsigned u1 = (__float_as_uint(hn1) + 0x80u) >> 8;
      const unsigned long long pk =
          ((unsigned long long)(nt | (u1 & 0x00FFFFFFu)) << 32) |
          (nt | (u0 & 0x00FFFFFFu));
      if (lane < NREG) {
        __hip_atomic_store(hpk + ((size_t)lane * 2 + ((t + 1) & 1)) * (HID / 2) + gw,
                           pk, __ATOMIC_RELEASE, __HIP_MEMORY_SCOPE_AGENT);
      }
    }

    // designated block writes out row t-1 (== staged h_t, fp24) coalesced
    if (t > 0 && (t & (NBLK - 1)) == blockIdx.x) {
      float* orow = out + (size_t)(t - 1) * HID;
      *(float4*)(orow + tid * 4) = v0;
      *(float4*)(orow + 1024 + tid * 4) = v1;
    }

    if (t == SEQ - 1 && lane == 0) {
      float2 hv2; hv2.x = hn0; hv2.y = hn1;
      *(float2*)(out + (size_t)t * HID + i0) = hv2;          // last out row (exact fp32)
      *(float2*)(out + (size_t)SEQ * HID + i0) = hv2;        // final hidden x2
      *(float2*)(out + (size_t)SEQ * HID + HID + i0) = hv2;
    }

    gr = pr; gz = pz; gn = pn;
  }
}

// ---------------------------------------------------------------------------
extern "C" void kernel_launch(void* const* d_in, const int* in_sizes, int n_in,
                              void* d_out, int out_size, void* d_ws, size_t ws_size,
                              hipStream_t stream) {
  const float* x    = (const float*)d_in[0];
  const float* w_ih = (const float*)d_in[1];
  const float* w_hh = (const float*)d_in[2];
  const float* b_ih = (const float*)d_in[3];
  const float* b_hh = (const float*)d_in[4];
  float* out = (float*)d_out;

  const size_t hpk_bytes = (size_t)NREG * 2 * (HID / 2) * 8;   // 128 KB

  int chunk = SEQ;
  while (chunk > 128 &&
         (size_t)chunk * N3 * 4 + hpk_bytes + 256 > ws_size)
    chunk >>= 1;

  const size_t gi_bytes = (size_t)chunk * N3 * 4;
  float* gi = (float*)d_ws;
  unsigned long long* hpk = (unsigned long long*)((char*)d_ws + gi_bytes);

  // h_0 = 0.0f tagged 0 == all-zero bytes; clears all regions
  (void)hipMemsetAsync(hpk, 0, hpk_bytes, stream);

  for (int t0 = 0; t0 < SEQ; t0 += chunk) {
    dim3 ggrid(N3 / BN, chunk / BM);
    gi_gemm_kernel<<<ggrid, 256, 0, stream>>>(x + (size_t)t0 * HID, w_ih, b_ih, gi);
    gru_recurrent_kernel<<<NBLK, 256, 0, stream>>>(w_hh, b_hh, gi, out, hpk,
                                                   t0, t0 + chunk);
  }
}

// Round 11
// 6139.249 us; speedup vs baseline: 16.5469x; 16.5469x over previous
//
#include <hip/hip_runtime.h>
#include <math.h>

#define HID 2048
#define SEQ 2048
#define N3  6144   // 3*HID
#define NBLK 256
#define NREG 8     // replicated exchange regions (contention spread)

// ---------------------------------------------------------------------------
// GEMM: GI = X @ W_ih^T + b_ih   (fp32, classic 128x128x16 LDS tile, 8x8/thread)
// ---------------------------------------------------------------------------
#define BM 128
#define BN 128
#define BK 16

__global__ __launch_bounds__(256)
void gi_gemm_kernel(const float* __restrict__ X, const float* __restrict__ W,
                    const float* __restrict__ bias, float* __restrict__ GI) {
  __shared__ float As[BK][BM + 4];
  __shared__ float Bs[BK][BN + 4];
  const int tid = threadIdx.x;
  const int bm = blockIdx.y * BM;
  const int bn = blockIdx.x * BN;
  const int tx = tid & 15;
  const int ty = tid >> 4;
  const int lr = tid >> 1;
  const int lk = (tid & 1) * 8;

  float acc[8][8];
#pragma unroll
  for (int i = 0; i < 8; ++i)
#pragma unroll
    for (int j = 0; j < 8; ++j) acc[i][j] = 0.f;

  const float* Arow = X + (size_t)(bm + lr) * HID + lk;
  const float* Brow = W + (size_t)(bn + lr) * HID + lk;

  for (int kc = 0; kc < HID; kc += BK) {
    float4 a0 = *(const float4*)(Arow + kc);
    float4 a1 = *(const float4*)(Arow + kc + 4);
    float4 b0 = *(const float4*)(Brow + kc);
    float4 b1 = *(const float4*)(Brow + kc + 4);
    __syncthreads();
    As[lk + 0][lr] = a0.x; As[lk + 1][lr] = a0.y; As[lk + 2][lr] = a0.z; As[lk + 3][lr] = a0.w;
    As[lk + 4][lr] = a1.x; As[lk + 5][lr] = a1.y; As[lk + 6][lr] = a1.z; As[lk + 7][lr] = a1.w;
    Bs[lk + 0][lr] = b0.x; Bs[lk + 1][lr] = b0.y; Bs[lk + 2][lr] = b0.z; Bs[lk + 3][lr] = b0.w;
    Bs[lk + 4][lr] = b1.x; Bs[lk + 5][lr] = b1.y; Bs[lk + 6][lr] = b1.z; Bs[lk + 7][lr] = b1.w;
    __syncthreads();
#pragma unroll
    for (int kk = 0; kk < BK; ++kk) {
      float4 av0 = *(const float4*)&As[kk][ty * 8];
      float4 av1 = *(const float4*)&As[kk][ty * 8 + 4];
      float4 bv0 = *(const float4*)&Bs[kk][tx * 8];
      float4 bv1 = *(const float4*)&Bs[kk][tx * 8 + 4];
      float a[8] = {av0.x, av0.y, av0.z, av0.w, av1.x, av1.y, av1.z, av1.w};
      float b[8] = {bv0.x, bv0.y, bv0.z, bv0.w, bv1.x, bv1.y, bv1.z, bv1.w};
#pragma unroll
      for (int i = 0; i < 8; ++i)
#pragma unroll
        for (int j = 0; j < 8; ++j)
          acc[i][j] = fmaf(a[i], b[j], acc[i][j]);
    }
  }

  const int n0 = bn + tx * 8;
  float bv[8];
#pragma unroll
  for (int j = 0; j < 8; ++j) bv[j] = bias[n0 + j];
#pragma unroll
  for (int i = 0; i < 8; ++i) {
    float4 o0, o1;
    o0.x = acc[i][0] + bv[0]; o0.y = acc[i][1] + bv[1];
    o0.z = acc[i][2] + bv[2]; o0.w = acc[i][3] + bv[3];
    o1.x = acc[i][4] + bv[4]; o1.y = acc[i][5] + bv[5];
    o1.z = acc[i][6] + bv[6]; o1.w = acc[i][7] + bv[7];
    float* Crow = GI + (size_t)(bm + ty * 8 + i) * N3 + n0;
    *(float4*)Crow = o0;
    *(float4*)(Crow + 4) = o1;
  }
}

// ---------------------------------------------------------------------------
// Persistent recurrent kernel == R9 (RELAXED atomics — R10's acquire was a
// 19x regression: buffer_inv per retry nukes the memory pipe). Single change:
// GI prefetch loads are issued BEFORE the poll loads, so the in-order vmcnt
// wait of the poll covers the ~900-cyc HBM GI load (overlap) instead of the
// barrier draining it serially after the poll (R9) or the next poll paying
// it (R8).
// ---------------------------------------------------------------------------
__device__ __forceinline__ unsigned long long ld_pair(const unsigned long long* p) {
  return __hip_atomic_load(p, __ATOMIC_RELAXED, __HIP_MEMORY_SCOPE_AGENT);
}

template <int CTRL, int ROW_MASK>
__device__ __forceinline__ float dpp_add(float x) {
  int y = __builtin_amdgcn_update_dpp(0, __float_as_uint(x), CTRL, ROW_MASK, 0xf, true);
  return x + __uint_as_float(y);
}

__device__ __forceinline__ float wave_sum(float x) {
  x = dpp_add<0x111, 0xf>(x);  // row_shr:1
  x = dpp_add<0x112, 0xf>(x);  // row_shr:2
  x = dpp_add<0x114, 0xf>(x);  // row_shr:4
  x = dpp_add<0x118, 0xf>(x);  // row_shr:8
  x = dpp_add<0x142, 0xa>(x);  // row_bcast:15, rows 1,3
  x = dpp_add<0x143, 0xc>(x);  // row_bcast:31, rows 2,3
  return __uint_as_float(__builtin_amdgcn_readlane(__float_as_uint(x), 63));
}

__device__ __forceinline__ float rlane(float x, int l) {
  return __uint_as_float(__builtin_amdgcn_readlane(__float_as_uint(x), l));
}

__device__ __forceinline__ float sigf(float x) {
  return __builtin_amdgcn_rcpf(1.f + __expf(-x));
}
__device__ __forceinline__ float tanhfast(float x) {
  return 1.f - 2.f * __builtin_amdgcn_rcpf(1.f + __expf(2.f * x));
}

__device__ __forceinline__ float unpk24(unsigned u) {           // low 24 bits -> fp32
  return __uint_as_float((u & 0x00FFFFFFu) << 8);
}

__global__ __launch_bounds__(256, 1)
void gru_recurrent_kernel(const float* __restrict__ Whh,
                          const float* __restrict__ bhh,
                          const float* __restrict__ GI,      // [t1-t0][N3]
                          float* __restrict__ out,
                          unsigned long long* hpk,           // [NREG][2][HID/2]
                          int t0, int t1) {
  __shared__ float lds_h[2][HID];
  const int tid  = threadIdx.x;
  const int lane = tid & 63;
  const int wv   = tid >> 6;
  const int gw   = blockIdx.x * 4 + wv;   // 0..1023 == this wave's pair-slot
  const int i0   = 2 * gw;
  const int reg  = blockIdx.x & (NREG - 1);

  const int rows[6] = {i0, i0 + 1, HID + i0, HID + i0 + 1, 2 * HID + i0, 2 * HID + i0 + 1};

  // Weights pinned in AGPRs: w[r][jb] covers k = jb*256 + lane*4 + {0..3}
  float4 w[6][8];
#pragma unroll
  for (int r = 0; r < 6; ++r) {
    const float* wr = Whh + (size_t)rows[r] * HID + lane * 4;
#pragma unroll
    for (int jb = 0; jb < 8; ++jb) {
      w[r][jb] = *(const float4*)(wr + jb * 256);
      asm volatile("" : "+a"(w[r][jb].x), "+a"(w[r][jb].y),
                        "+a"(w[r][jb].z), "+a"(w[r][jb].w));
    }
  }

  // wave-uniform biases for the wave's two units
  float br0, br1, bz0, bz1, bn0, bn1;
  {
    float a = 0.f, b = 0.f, c = 0.f;
    if (lane < 2) {
      a = bhh[i0 + lane];
      b = bhh[HID + i0 + lane];
      c = bhh[2 * HID + i0 + lane];
    }
    br0 = rlane(a, 0); br1 = rlane(a, 1);
    bz0 = rlane(b, 0); bz1 = rlane(b, 1);
    bn0 = rlane(c, 0); bn1 = rlane(c, 1);
  }

  // GI prefetch for first step
  float gr = 0.f, gz = 0.f, gn = 0.f;
  if (lane < 2) {
    gr = GI[i0 + lane];
    gz = GI[HID + i0 + lane];
    gn = GI[2 * HID + i0 + lane];
  }

  const int s0 = tid * 2;   // this thread's first pair-slot in each half

  for (int t = t0; t < t1; ++t) {
    // ---- issue NEXT step's GI loads FIRST: the poll's in-order vmcnt wait
    //      then covers this HBM latency (overlap instead of serial drain) ----
    float pr = 0.f, pz = 0.f, pn = 0.f;
    if (t + 1 < t1 && lane < 2) {
      const float* g = GI + (size_t)(t + 1 - t0) * N3;
      pr = g[i0 + lane];
      pz = g[HID + i0 + lane];
      pn = g[2 * HID + i0 + lane];
    }
    asm volatile("" ::: "memory");   // keep GI loads issued before poll loads

    // ---- batched-retry poll: 4 packed pair-slots (8 units) per thread ----
    const unsigned long long* hb = hpk + ((size_t)reg * 2 + (t & 1)) * (HID / 2);
    const unsigned tb = (unsigned)t & 0xFFu;
    const unsigned long long pat =
        ((unsigned long long)tb << 24) | ((unsigned long long)tb << 56);
    const unsigned long long msk = 0xFF000000FF000000ULL;
    unsigned long long q0 = ld_pair(hb + s0);
    unsigned long long q1 = ld_pair(hb + s0 + 1);
    unsigned long long q2 = ld_pair(hb + 512 + s0);
    unsigned long long q3 = ld_pair(hb + 512 + s0 + 1);
    for (;;) {
      int stale = 0;
      stale |= ((q0 & msk) != pat) ? 1 : 0;
      stale |= ((q1 & msk) != pat) ? 2 : 0;
      stale |= ((q2 & msk) != pat) ? 4 : 0;
      stale |= ((q3 & msk) != pat) ? 8 : 0;
      if (!stale) break;
      if (stale & 1) q0 = ld_pair(hb + s0);
      if (stale & 2) q1 = ld_pair(hb + s0 + 1);
      if (stale & 4) q2 = ld_pair(hb + 512 + s0);
      if (stale & 8) q3 = ld_pair(hb + 512 + s0 + 1);
    }

    float* lc = lds_h[t & 1];
    float4 v0, v1;
    v0.x = unpk24((unsigned)q0); v0.y = unpk24((unsigned)(q0 >> 32));
    v0.z = unpk24((unsigned)q1); v0.w = unpk24((unsigned)(q1 >> 32));
    v1.x = unpk24((unsigned)q2); v1.y = unpk24((unsigned)(q2 >> 32));
    v1.z = unpk24((unsigned)q3); v1.w = unpk24((unsigned)(q3 >> 32));
    *(float4*)&lc[tid * 4] = v0;
    *(float4*)&lc[1024 + tid * 4] = v1;
    __syncthreads();

    // ---- matvec: 6 rows x 2048 (weights in AGPRs) ----
    float acc0 = 0.f, acc1 = 0.f, acc2 = 0.f, acc3 = 0.f, acc4 = 0.f, acc5 = 0.f;
#pragma unroll
    for (int jb = 0; jb < 8; ++jb) {
      float4 hv = *(const float4*)&lc[jb * 256 + lane * 4];
      acc0 = fmaf(w[0][jb].x, hv.x, acc0); acc0 = fmaf(w[0][jb].y, hv.y, acc0);
      acc0 = fmaf(w[0][jb].z, hv.z, acc0); acc0 = fmaf(w[0][jb].w, hv.w, acc0);
      acc1 = fmaf(w[1][jb].x, hv.x, acc1); acc1 = fmaf(w[1][jb].y, hv.y, acc1);
      acc1 = fmaf(w[1][jb].z, hv.z, acc1); acc1 = fmaf(w[1][jb].w, hv.w, acc1);
      acc2 = fmaf(w[2][jb].x, hv.x, acc2); acc2 = fmaf(w[2][jb].y, hv.y, acc2);
      acc2 = fmaf(w[2][jb].z, hv.z, acc2); acc2 = fmaf(w[2][jb].w, hv.w, acc2);
      acc3 = fmaf(w[3][jb].x, hv.x, acc3); acc3 = fmaf(w[3][jb].y, hv.y, acc3);
      acc3 = fmaf(w[3][jb].z, hv.z, acc3); acc3 = fmaf(w[3][jb].w, hv.w, acc3);
      acc4 = fmaf(w[4][jb].x, hv.x, acc4); acc4 = fmaf(w[4][jb].y, hv.y, acc4);
      acc4 = fmaf(w[4][jb].z, hv.z, acc4); acc4 = fmaf(w[4][jb].w, hv.w, acc4);
      acc5 = fmaf(w[5][jb].x, hv.x, acc5); acc5 = fmaf(w[5][jb].y, hv.y, acc5);
      acc5 = fmaf(w[5][jb].z, hv.z, acc5); acc5 = fmaf(w[5][jb].w, hv.w, acc5);
    }

    // ---- DPP reduce -> wave-uniform sums ----
    const float sr0 = wave_sum(acc0), sr1 = wave_sum(acc1);
    const float sz0 = wave_sum(acc2), sz1 = wave_sum(acc3);
    const float sn0 = wave_sum(acc4), sn1 = wave_sum(acc5);

    const float gr0 = rlane(gr, 0), gr1 = rlane(gr, 1);
    const float gz0 = rlane(gz, 0), gz1 = rlane(gz, 1);
    const float gn0 = rlane(gn, 0), gn1 = rlane(gn, 1);

    const float r0 = sigf(gr0 + sr0 + br0);
    const float r1 = sigf(gr1 + sr1 + br1);
    const float z0 = sigf(gz0 + sz0 + bz0);
    const float z1 = sigf(gz1 + sz1 + bz1);
    const float n0 = tanhfast(gn0 + r0 * (sn0 + bn0));
    const float n1 = tanhfast(gn1 + r1 * (sn1 + bn1));
    const float hp0 = lc[i0], hp1 = lc[i0 + 1];
    const float hn0 = (1.f - z0) * n0 + z0 * hp0;   // wave-uniform
    const float hn1 = (1.f - z1) * n1 + z1 * hp1;   // wave-uniform

    // ---- pack (tag8|fp24)x2 and store to 8 regions with ONE instruction ----
    {
      const unsigned nt = ((unsigned)(t + 1) & 0xFFu) << 24;
      const unsigned u0 = (__float_as_uint(hn0) + 0x80u) >> 8;   // round-half-up
      const unsigned u1 = (__float_as_uint(hn1) + 0x80u) >> 8;
      const unsigned long long pk =
          ((unsigned long long)(nt | (u1 & 0x00FFFFFFu)) << 32) |
          (nt | (u0 & 0x00FFFFFFu));
      if (lane < NREG) {
        __hip_atomic_store(hpk + ((size_t)lane * 2 + ((t + 1) & 1)) * (HID / 2) + gw,
                           pk, __ATOMIC_RELAXED, __HIP_MEMORY_SCOPE_AGENT);
      }
    }

    // designated block writes out row t-1 (== staged h_t, fp24) coalesced
    if (t > 0 && (t & (NBLK - 1)) == blockIdx.x) {
      float* orow = out + (size_t)(t - 1) * HID;
      *(float4*)(orow + tid * 4) = v0;
      *(float4*)(orow + 1024 + tid * 4) = v1;
    }

    if (t == SEQ - 1 && lane == 0) {
      float2 hv2; hv2.x = hn0; hv2.y = hn1;
      *(float2*)(out + (size_t)t * HID + i0) = hv2;          // last out row (exact fp32)
      *(float2*)(out + (size_t)SEQ * HID + i0) = hv2;        // final hidden x2
      *(float2*)(out + (size_t)SEQ * HID + HID + i0) = hv2;
    }

    gr = pr; gz = pz; gn = pn;
  }
}

// ---------------------------------------------------------------------------
extern "C" void kernel_launch(void* const* d_in, const int* in_sizes, int n_in,
                              void* d_out, int out_size, void* d_ws, size_t ws_size,
                              hipStream_t stream) {
  const float* x    = (const float*)d_in[0];
  const float* w_ih = (const float*)d_in[1];
  const float* w_hh = (const float*)d_in[2];
  const float* b_ih = (const float*)d_in[3];
  const float* b_hh = (const float*)d_in[4];
  float* out = (float*)d_out;

  const size_t hpk_bytes = (size_t)NREG * 2 * (HID / 2) * 8;   // 128 KB

  int chunk = SEQ;
  while (chunk > 128 &&
         (size_t)chunk * N3 * 4 + hpk_bytes + 256 > ws_size)
    chunk >>= 1;

  const size_t gi_bytes = (size_t)chunk * N3 * 4;
  float* gi = (float*)d_ws;
  unsigned long long* hpk = (unsigned long long*)((char*)d_ws + gi_bytes);

  // h_0 = 0.0f tagged 0 == all-zero bytes; clears all regions
  (void)hipMemsetAsync(hpk, 0, hpk_bytes, stream);

  for (int t0 = 0; t0 < SEQ; t0 += chunk) {
    dim3 ggrid(N3 / BN, chunk / BM);
    gi_gemm_kernel<<<ggrid, 256, 0, stream>>>(x + (size_t)t0 * HID, w_ih, b_ih, gi);
    gru_recurrent_kernel<<<NBLK, 256, 0, stream>>>(w_hh, b_hh, gi, out, hpk,
                                                   t0, t0 + chunk);
  }
}

// Round 12
// 5145.380 us; speedup vs baseline: 19.7430x; 1.1932x over previous
//
#include <hip/hip_runtime.h>
#include <math.h>

#define HID 2048
#define SEQ 2048
#define N3  6144   // 3*HID
#define NBLK 256
#define NREG 8     // replicated exchange regions (contention spread)

// ---------------------------------------------------------------------------
// GEMM: GI = X @ W_ih^T + b_ih   (fp32, classic 128x128x16 LDS tile, 8x8/thread)
// ---------------------------------------------------------------------------
#define BM 128
#define BN 128
#define BK 16

__global__ __launch_bounds__(256)
void gi_gemm_kernel(const float* __restrict__ X, const float* __restrict__ W,
                    const float* __restrict__ bias, float* __restrict__ GI) {
  __shared__ float As[BK][BM + 4];
  __shared__ float Bs[BK][BN + 4];
  const int tid = threadIdx.x;
  const int bm = blockIdx.y * BM;
  const int bn = blockIdx.x * BN;
  const int tx = tid & 15;
  const int ty = tid >> 4;
  const int lr = tid >> 1;
  const int lk = (tid & 1) * 8;

  float acc[8][8];
#pragma unroll
  for (int i = 0; i < 8; ++i)
#pragma unroll
    for (int j = 0; j < 8; ++j) acc[i][j] = 0.f;

  const float* Arow = X + (size_t)(bm + lr) * HID + lk;
  const float* Brow = W + (size_t)(bn + lr) * HID + lk;

  for (int kc = 0; kc < HID; kc += BK) {
    float4 a0 = *(const float4*)(Arow + kc);
    float4 a1 = *(const float4*)(Arow + kc + 4);
    float4 b0 = *(const float4*)(Brow + kc);
    float4 b1 = *(const float4*)(Brow + kc + 4);
    __syncthreads();
    As[lk + 0][lr] = a0.x; As[lk + 1][lr] = a0.y; As[lk + 2][lr] = a0.z; As[lk + 3][lr] = a0.w;
    As[lk + 4][lr] = a1.x; As[lk + 5][lr] = a1.y; As[lk + 6][lr] = a1.z; As[lk + 7][lr] = a1.w;
    Bs[lk + 0][lr] = b0.x; Bs[lk + 1][lr] = b0.y; Bs[lk + 2][lr] = b0.z; Bs[lk + 3][lr] = b0.w;
    Bs[lk + 4][lr] = b1.x; Bs[lk + 5][lr] = b1.y; Bs[lk + 6][lr] = b1.z; Bs[lk + 7][lr] = b1.w;
    __syncthreads();
#pragma unroll
    for (int kk = 0; kk < BK; ++kk) {
      float4 av0 = *(const float4*)&As[kk][ty * 8];
      float4 av1 = *(const float4*)&As[kk][ty * 8 + 4];
      float4 bv0 = *(const float4*)&Bs[kk][tx * 8];
      float4 bv1 = *(const float4*)&Bs[kk][tx * 8 + 4];
      float a[8] = {av0.x, av0.y, av0.z, av0.w, av1.x, av1.y, av1.z, av1.w};
      float b[8] = {bv0.x, bv0.y, bv0.z, bv0.w, bv1.x, bv1.y, bv1.z, bv1.w};
#pragma unroll
      for (int i = 0; i < 8; ++i)
#pragma unroll
        for (int j = 0; j < 8; ++j)
          acc[i][j] = fmaf(a[i], b[j], acc[i][j]);
    }
  }

  const int n0 = bn + tx * 8;
  float bv[8];
#pragma unroll
  for (int j = 0; j < 8; ++j) bv[j] = bias[n0 + j];
#pragma unroll
  for (int i = 0; i < 8; ++i) {
    float4 o0, o1;
    o0.x = acc[i][0] + bv[0]; o0.y = acc[i][1] + bv[1];
    o0.z = acc[i][2] + bv[2]; o0.w = acc[i][3] + bv[3];
    o1.x = acc[i][4] + bv[4]; o1.y = acc[i][5] + bv[5];
    o1.z = acc[i][6] + bv[6]; o1.w = acc[i][7] + bv[7];
    float* Crow = GI + (size_t)(bm + ty * 8 + i) * N3 + n0;
    *(float4*)Crow = o0;
    *(float4*)(Crow + 4) = o1;
  }
}

// ---------------------------------------------------------------------------
// Persistent recurrent kernel == R11 + RHYTHM PACING: each wave tracks the
// inter-step detection period (s_memtime EMA) and delays its poll until
// (prev_detect + period - margin) with a pure SCALAR clock spin (zero memory
// traffic). This removes ~90% of poll load-requests, letting producer stores
// drain to L3 promptly (poll traffic was delaying the very stores that end
// the polling). Tags still verify — pacing is a heuristic delay only.
// ---------------------------------------------------------------------------
__device__ __forceinline__ unsigned long long ld_pair(const unsigned long long* p) {
  return __hip_atomic_load(p, __ATOMIC_RELAXED, __HIP_MEMORY_SCOPE_AGENT);
}

template <int CTRL, int ROW_MASK>
__device__ __forceinline__ float dpp_add(float x) {
  int y = __builtin_amdgcn_update_dpp(0, __float_as_uint(x), CTRL, ROW_MASK, 0xf, true);
  return x + __uint_as_float(y);
}

__device__ __forceinline__ float wave_sum(float x) {
  x = dpp_add<0x111, 0xf>(x);  // row_shr:1
  x = dpp_add<0x112, 0xf>(x);  // row_shr:2
  x = dpp_add<0x114, 0xf>(x);  // row_shr:4
  x = dpp_add<0x118, 0xf>(x);  // row_shr:8
  x = dpp_add<0x142, 0xa>(x);  // row_bcast:15, rows 1,3
  x = dpp_add<0x143, 0xc>(x);  // row_bcast:31, rows 2,3
  return __uint_as_float(__builtin_amdgcn_readlane(__float_as_uint(x), 63));
}

__device__ __forceinline__ float rlane(float x, int l) {
  return __uint_as_float(__builtin_amdgcn_readlane(__float_as_uint(x), l));
}

__device__ __forceinline__ float sigf(float x) {
  return __builtin_amdgcn_rcpf(1.f + __expf(-x));
}
__device__ __forceinline__ float tanhfast(float x) {
  return 1.f - 2.f * __builtin_amdgcn_rcpf(1.f + __expf(2.f * x));
}

__device__ __forceinline__ float unpk24(unsigned u) {           // low 24 bits -> fp32
  return __uint_as_float((u & 0x00FFFFFFu) << 8);
}

__global__ __launch_bounds__(256, 1)
void gru_recurrent_kernel(const float* __restrict__ Whh,
                          const float* __restrict__ bhh,
                          const float* __restrict__ GI,      // [t1-t0][N3]
                          float* __restrict__ out,
                          unsigned long long* hpk,           // [NREG][2][HID/2]
                          int t0, int t1) {
  __shared__ float lds_h[2][HID];
  const int tid  = threadIdx.x;
  const int lane = tid & 63;
  const int wv   = tid >> 6;
  const int gw   = blockIdx.x * 4 + wv;   // 0..1023 == this wave's pair-slot
  const int i0   = 2 * gw;
  const int reg  = blockIdx.x & (NREG - 1);

  const int rows[6] = {i0, i0 + 1, HID + i0, HID + i0 + 1, 2 * HID + i0, 2 * HID + i0 + 1};

  // Weights pinned in AGPRs: w[r][jb] covers k = jb*256 + lane*4 + {0..3}
  float4 w[6][8];
#pragma unroll
  for (int r = 0; r < 6; ++r) {
    const float* wr = Whh + (size_t)rows[r] * HID + lane * 4;
#pragma unroll
    for (int jb = 0; jb < 8; ++jb) {
      w[r][jb] = *(const float4*)(wr + jb * 256);
      asm volatile("" : "+a"(w[r][jb].x), "+a"(w[r][jb].y),
                        "+a"(w[r][jb].z), "+a"(w[r][jb].w));
    }
  }

  // wave-uniform biases for the wave's two units
  float br0, br1, bz0, bz1, bn0, bn1;
  {
    float a = 0.f, b = 0.f, c = 0.f;
    if (lane < 2) {
      a = bhh[i0 + lane];
      b = bhh[HID + i0 + lane];
      c = bhh[2 * HID + i0 + lane];
    }
    br0 = rlane(a, 0); br1 = rlane(a, 1);
    bz0 = rlane(b, 0); bz1 = rlane(b, 1);
    bn0 = rlane(c, 0); bn1 = rlane(c, 1);
  }

  // GI prefetch for first step
  float gr = 0.f, gz = 0.f, gn = 0.f;
  if (lane < 2) {
    gr = GI[i0 + lane];
    gz = GI[HID + i0 + lane];
    gn = GI[2 * HID + i0 + lane];
  }

  const int s0 = tid * 2;   // this thread's first pair-slot in each half

  // rhythm pacing state (scalar, wave-uniform in practice)
  long long d_prev = 0;     // detect timestamp of previous step
  long long period = 0;     // EMA of inter-step period (cycles)
  const long long MARGIN = 1500;

  for (int t = t0; t < t1; ++t) {
    // ---- pace: scalar-clock spin until just before expected data arrival ----
    if (period > 0) {
      const long long target = d_prev + period - MARGIN;
      while ((long long)__builtin_amdgcn_s_memtime() < target)
        __builtin_amdgcn_s_sleep(1);
    }

    // ---- issue NEXT step's GI loads FIRST (poll's vmcnt wait covers them) ----
    float pr = 0.f, pz = 0.f, pn = 0.f;
    if (t + 1 < t1 && lane < 2) {
      const float* g = GI + (size_t)(t + 1 - t0) * N3;
      pr = g[i0 + lane];
      pz = g[HID + i0 + lane];
      pn = g[2 * HID + i0 + lane];
    }
    asm volatile("" ::: "memory");   // keep GI loads issued before poll loads

    // ---- batched-retry poll: 4 packed pair-slots (8 units) per thread ----
    const unsigned long long* hb = hpk + ((size_t)reg * 2 + (t & 1)) * (HID / 2);
    const unsigned tb = (unsigned)t & 0xFFu;
    const unsigned long long pat =
        ((unsigned long long)tb << 24) | ((unsigned long long)tb << 56);
    const unsigned long long msk = 0xFF000000FF000000ULL;
    unsigned long long q0 = ld_pair(hb + s0);
    unsigned long long q1 = ld_pair(hb + s0 + 1);
    unsigned long long q2 = ld_pair(hb + 512 + s0);
    unsigned long long q3 = ld_pair(hb + 512 + s0 + 1);
    for (;;) {
      int stale = 0;
      stale |= ((q0 & msk) != pat) ? 1 : 0;
      stale |= ((q1 & msk) != pat) ? 2 : 0;
      stale |= ((q2 & msk) != pat) ? 4 : 0;
      stale |= ((q3 & msk) != pat) ? 8 : 0;
      if (!stale) break;
      if (stale & 1) q0 = ld_pair(hb + s0);
      if (stale & 2) q1 = ld_pair(hb + s0 + 1);
      if (stale & 4) q2 = ld_pair(hb + 512 + s0);
      if (stale & 8) q3 = ld_pair(hb + 512 + s0 + 1);
    }

    // ---- update pacing EMA with this step's detect time ----
    {
      const long long now = (long long)__builtin_amdgcn_s_memtime();
      if (d_prev > 0) {
        const long long iv = now - d_prev;
        period = (period > 0) ? period + ((iv - period) >> 3) : iv;
        if (period > 20000) period = 20000;
        if (period < 0) period = 0;
      }
      d_prev = now;
    }

    float* lc = lds_h[t & 1];
    float4 v0, v1;
    v0.x = unpk24((unsigned)q0); v0.y = unpk24((unsigned)(q0 >> 32));
    v0.z = unpk24((unsigned)q1); v0.w = unpk24((unsigned)(q1 >> 32));
    v1.x = unpk24((unsigned)q2); v1.y = unpk24((unsigned)(q2 >> 32));
    v1.z = unpk24((unsigned)q3); v1.w = unpk24((unsigned)(q3 >> 32));
    *(float4*)&lc[tid * 4] = v0;
    *(float4*)&lc[1024 + tid * 4] = v1;
    __syncthreads();

    // ---- matvec: 6 rows x 2048 (weights in AGPRs) ----
    float acc0 = 0.f, acc1 = 0.f, acc2 = 0.f, acc3 = 0.f, acc4 = 0.f, acc5 = 0.f;
#pragma unroll
    for (int jb = 0; jb < 8; ++jb) {
      float4 hv = *(const float4*)&lc[jb * 256 + lane * 4];
      acc0 = fmaf(w[0][jb].x, hv.x, acc0); acc0 = fmaf(w[0][jb].y, hv.y, acc0);
      acc0 = fmaf(w[0][jb].z, hv.z, acc0); acc0 = fmaf(w[0][jb].w, hv.w, acc0);
      acc1 = fmaf(w[1][jb].x, hv.x, acc1); acc1 = fmaf(w[1][jb].y, hv.y, acc1);
      acc1 = fmaf(w[1][jb].z, hv.z, acc1); acc1 = fmaf(w[1][jb].w, hv.w, acc1);
      acc2 = fmaf(w[2][jb].x, hv.x, acc2); acc2 = fmaf(w[2][jb].y, hv.y, acc2);
      acc2 = fmaf(w[2][jb].z, hv.z, acc2); acc2 = fmaf(w[2][jb].w, hv.w, acc2);
      acc3 = fmaf(w[3][jb].x, hv.x, acc3); acc3 = fmaf(w[3][jb].y, hv.y, acc3);
      acc3 = fmaf(w[3][jb].z, hv.z, acc3); acc3 = fmaf(w[3][jb].w, hv.w, acc3);
      acc4 = fmaf(w[4][jb].x, hv.x, acc4); acc4 = fmaf(w[4][jb].y, hv.y, acc4);
      acc4 = fmaf(w[4][jb].z, hv.z, acc4); acc4 = fmaf(w[4][jb].w, hv.w, acc4);
      acc5 = fmaf(w[5][jb].x, hv.x, acc5); acc5 = fmaf(w[5][jb].y, hv.y, acc5);
      acc5 = fmaf(w[5][jb].z, hv.z, acc5); acc5 = fmaf(w[5][jb].w, hv.w, acc5);
    }

    // ---- DPP reduce -> wave-uniform sums ----
    const float sr0 = wave_sum(acc0), sr1 = wave_sum(acc1);
    const float sz0 = wave_sum(acc2), sz1 = wave_sum(acc3);
    const float sn0 = wave_sum(acc4), sn1 = wave_sum(acc5);

    const float gr0 = rlane(gr, 0), gr1 = rlane(gr, 1);
    const float gz0 = rlane(gz, 0), gz1 = rlane(gz, 1);
    const float gn0 = rlane(gn, 0), gn1 = rlane(gn, 1);

    const float r0 = sigf(gr0 + sr0 + br0);
    const float r1 = sigf(gr1 + sr1 + br1);
    const float z0 = sigf(gz0 + sz0 + bz0);
    const float z1 = sigf(gz1 + sz1 + bz1);
    const float n0 = tanhfast(gn0 + r0 * (sn0 + bn0));
    const float n1 = tanhfast(gn1 + r1 * (sn1 + bn1));
    const float hp0 = lc[i0], hp1 = lc[i0 + 1];
    const float hn0 = (1.f - z0) * n0 + z0 * hp0;   // wave-uniform
    const float hn1 = (1.f - z1) * n1 + z1 * hp1;   // wave-uniform

    // ---- pack (tag8|fp24)x2 and store to 8 regions with ONE instruction ----
    {
      const unsigned nt = ((unsigned)(t + 1) & 0xFFu) << 24;
      const unsigned u0 = (__float_as_uint(hn0) + 0x80u) >> 8;   // round-half-up
      const unsigned u1 = (__float_as_uint(hn1) + 0x80u) >> 8;
      const unsigned long long pk =
          ((unsigned long long)(nt | (u1 & 0x00FFFFFFu)) << 32) |
          (nt | (u0 & 0x00FFFFFFu));
      if (lane < NREG) {
        __hip_atomic_store(hpk + ((size_t)lane * 2 + ((t + 1) & 1)) * (HID / 2) + gw,
                           pk, __ATOMIC_RELAXED, __HIP_MEMORY_SCOPE_AGENT);
      }
    }

    // designated block writes out row t-1 (== staged h_t, fp24) coalesced
    if (t > 0 && (t & (NBLK - 1)) == blockIdx.x) {
      float* orow = out + (size_t)(t - 1) * HID;
      *(float4*)(orow + tid * 4) = v0;
      *(float4*)(orow + 1024 + tid * 4) = v1;
    }

    if (t == SEQ - 1 && lane == 0) {
      float2 hv2; hv2.x = hn0; hv2.y = hn1;
      *(float2*)(out + (size_t)t * HID + i0) = hv2;          // last out row (exact fp32)
      *(float2*)(out + (size_t)SEQ * HID + i0) = hv2;        // final hidden x2
      *(float2*)(out + (size_t)SEQ * HID + HID + i0) = hv2;
    }

    gr = pr; gz = pz; gn = pn;
  }
}

// ---------------------------------------------------------------------------
extern "C" void kernel_launch(void* const* d_in, const int* in_sizes, int n_in,
                              void* d_out, int out_size, void* d_ws, size_t ws_size,
                              hipStream_t stream) {
  const float* x    = (const float*)d_in[0];
  const float* w_ih = (const float*)d_in[1];
  const float* w_hh = (const float*)d_in[2];
  const float* b_ih = (const float*)d_in[3];
  const float* b_hh = (const float*)d_in[4];
  float* out = (float*)d_out;

  const size_t hpk_bytes = (size_t)NREG * 2 * (HID / 2) * 8;   // 128 KB

  int chunk = SEQ;
  while (chunk > 128 &&
         (size_t)chunk * N3 * 4 + hpk_bytes + 256 > ws_size)
    chunk >>= 1;

  const size_t gi_bytes = (size_t)chunk * N3 * 4;
  float* gi = (float*)d_ws;
  unsigned long long* hpk = (unsigned long long*)((char*)d_ws + gi_bytes);

  // h_0 = 0.0f tagged 0 == all-zero bytes; clears all regions
  (void)hipMemsetAsync(hpk, 0, hpk_bytes, stream);

  for (int t0 = 0; t0 < SEQ; t0 += chunk) {
    dim3 ggrid(N3 / BN, chunk / BM);
    gi_gemm_kernel<<<ggrid, 256, 0, stream>>>(x + (size_t)t0 * HID, w_ih, b_ih, gi);
    gru_recurrent_kernel<<<NBLK, 256, 0, stream>>>(w_hh, b_hh, gi, out, hpk,
                                                   t0, t0 + chunk);
  }
}